// Round 5
// baseline (133.662 us; speedup 1.0000x reference)
//
#include <hip/hip_runtime.h>

typedef __bf16 bf16x8 __attribute__((ext_vector_type(8)));
typedef float f32x4 __attribute__((ext_vector_type(4)));

#define BS 4096
#define D 1024
#define M2 8192

#define BK 32
#define NKT (D / BK)     // 32 K-steps
#define NRECT 1024       // 128x256 upper-triangle pair-tiles
#define NDIA 32          // leftover 128x128 diagonal tiles (odd row-blocks)
#define NBLK_ALL 1056    // 1056 % 8 == 0

// workspace layout (bytes)
#define OFF_Z      ((size_t)0)
#define OFF_SUMEXP ((size_t)M2 * D * 2)          // 16 MiB of bf16 Z
#define OFF_POS    (OFF_SUMEXP + (size_t)M2 * 4)
#define OFF_DIO    (OFF_POS + (size_t)M2 * 4)
#define OFF_DJO    (OFF_DIO + (size_t)BS * 4)

static __device__ __forceinline__ unsigned short f2bf(float x) {
  union { float f; unsigned int u; } c; c.f = x;
  unsigned int u = c.u;
  return (unsigned short)((u + 0x7FFFu + ((u >> 16) & 1u)) >> 16);
}

static __device__ __forceinline__ void gload_lds16(const void* g, void* l) {
  __builtin_amdgcn_global_load_lds(
      (__attribute__((address_space(1))) void*)(uintptr_t)g,
      (__attribute__((address_space(3))) void*)(unsigned int)(uintptr_t)l,
      16, 0, 0);
}

// ---------------- kernel 1: normalize rows, emit bf16 Z, per-row dots, zero sumexp ----------------
__global__ __launch_bounds__(256) void prep_kernel(
    const float* __restrict__ zi, const float* __restrict__ zj,
    const float* __restrict__ zo, unsigned short* __restrict__ Z,
    float* __restrict__ dio, float* __restrict__ djo,
    float* __restrict__ sumexp) {
  const int r = blockIdx.x;
  const int tid = threadIdx.x;
  if (tid < 2) sumexp[2 * r + tid] = 0.f;   // replaces hipMemsetAsync
  const float4 vi = ((const float4*)(zi + (size_t)r * D))[tid];
  const float4 vj = ((const float4*)(zj + (size_t)r * D))[tid];
  const float4 vo = ((const float4*)(zo + (size_t)r * D))[tid];

  float s[5];
  s[0] = vi.x * vi.x + vi.y * vi.y + vi.z * vi.z + vi.w * vi.w;
  s[1] = vj.x * vj.x + vj.y * vj.y + vj.z * vj.z + vj.w * vj.w;
  s[2] = vo.x * vo.x + vo.y * vo.y + vo.z * vo.z + vo.w * vo.w;
  s[3] = vi.x * vo.x + vi.y * vo.y + vi.z * vo.z + vi.w * vo.w;
  s[4] = vj.x * vo.x + vj.y * vo.y + vj.z * vo.z + vj.w * vo.w;

#pragma unroll
  for (int k = 0; k < 5; ++k)
#pragma unroll
    for (int o = 32; o; o >>= 1) s[k] += __shfl_xor(s[k], o);

  __shared__ float red[4][5];
  const int w = tid >> 6, lane = tid & 63;
  if (lane == 0) {
#pragma unroll
    for (int k = 0; k < 5; ++k) red[w][k] = s[k];
  }
  __syncthreads();
  float tot[5];
#pragma unroll
  for (int k = 0; k < 5; ++k)
    tot[k] = red[0][k] + red[1][k] + red[2][k] + red[3][k];

  const float rsi = 1.0f / sqrtf(tot[0]);
  const float rsj = 1.0f / sqrtf(tot[1]);
  const float rso = 1.0f / sqrtf(tot[2]);

  ushort4 oi, oj;
  oi.x = f2bf(vi.x * rsi); oi.y = f2bf(vi.y * rsi);
  oi.z = f2bf(vi.z * rsi); oi.w = f2bf(vi.w * rsi);
  oj.x = f2bf(vj.x * rsj); oj.y = f2bf(vj.y * rsj);
  oj.z = f2bf(vj.z * rsj); oj.w = f2bf(vj.w * rsj);
  ((ushort4*)(Z + (size_t)r * D))[tid] = oi;
  ((ushort4*)(Z + (size_t)(BS + r) * D))[tid] = oj;

  if (tid == 0) {
    dio[r] = tot[3] * rsi * rso;
    djo[r] = tot[4] * rsj * rso;
  }
}

// ---------------- kernel 2: upper-triangle S = Z Z^T via 128x256 rect + 128^2 diag tiles ----------------
// Rect tile (rm, cn0): rows [rm*128, +128), cols [cn0*128, +256). 4 waves, wave-tile 128x64.
// Diag tile (rm==cn0, odd rm): classic 128^2, 4 waves, wave-tile 64x64, row-sums only.
__global__ __launch_bounds__(256, 2) void gemm_lse_kernel(
    const unsigned short* __restrict__ Z,
    float* __restrict__ sumexp, float* __restrict__ pos) {
  __shared__ __align__(16) __bf16 lA[3][128 * BK];
  __shared__ __align__(16) __bf16 lB[3][256 * BK];
  __shared__ float psumR[4][128];
  __shared__ float psumC[256];

  // XCD-bijective swizzle (1056 = 8 * 132)
  const int torig = blockIdx.x;
  const int t = (torig & 7) * (NBLK_ALL / 8) + (torig >> 3);

  // tile decode
  int rm, cn0;
  bool isRect;
  if (t < NRECT) {
    isRect = true;
    int rem = t;
    rm = 0;
    for (;;) {
      const int cnt = (rm & 1) ? ((63 - rm) >> 1) : ((64 - rm) >> 1);
      if (rem < cnt) break;
      rem -= cnt;
      ++rm;
    }
    cn0 = ((rm & 1) ? (rm + 1) : rm) + 2 * rem;
  } else {
    isRect = false;
    rm = 2 * (t - NRECT) + 1;   // odd diagonal cells
    cn0 = rm;
  }

  const int tid = threadIdx.x;
  const int lane = tid & 63, w = tid >> 6;
  const int lr = lane & 15, lg = lane >> 4;
  // LDS chunk swizzle: LDS(row, c) holds global chunk c ^ ((row>>1)&3).
  // Read side: global chunk lg at row r lives at LDS chunk lg ^ ((r>>1)&3);
  // all fragment rows have (r>>1)&3 == (lr>>1)&3.
  const int swz = (lg ^ ((lr >> 1) & 3)) * 8;

  // staging: thread tid owns row srow (+64k), swizzled source chunk
  const int srow = tid >> 2;
  const int schunk = (tid & 3) ^ ((srow >> 1) & 3);
  const unsigned short* gA = Z + (size_t)(rm * 128 + srow) * D + schunk * 8;
  const unsigned short* gB = Z + (size_t)(cn0 * 128 + srow) * D + schunk * 8;

  if (isRect) {
#define STAGE_R(buf)                                                 \
    do {                                                             \
      gload_lds16(gA, &lA[buf][tid * 8]);                            \
      gload_lds16(gA + (size_t)64 * D, &lA[buf][tid * 8 + 64 * BK]); \
      gload_lds16(gB, &lB[buf][tid * 8]);                            \
      gload_lds16(gB + (size_t)64 * D, &lB[buf][tid * 8 + 64 * BK]); \
      gload_lds16(gB + (size_t)128 * D, &lB[buf][tid * 8 + 128 * BK]); \
      gload_lds16(gB + (size_t)192 * D, &lB[buf][tid * 8 + 192 * BK]); \
      gA += BK; gB += BK;                                            \
    } while (0)

    f32x4 acc[8][4] = {};
    STAGE_R(0);
    STAGE_R(1);

    for (int kt = 0; kt < NKT; ++kt) {
      const int cur = kt % 3;
      if (kt < NKT - 2) {
        STAGE_R((kt + 2) % 3);
        asm volatile("s_waitcnt vmcnt(12)");   // tile-kt's 6 loads complete
      } else if (kt == NKT - 2) {
        asm volatile("s_waitcnt vmcnt(6)");
      } else {
        asm volatile("s_waitcnt vmcnt(0)");
      }
      __builtin_amdgcn_s_barrier();
      __builtin_amdgcn_sched_barrier(0);

      bf16x8 af[8], bfr[4];
#pragma unroll
      for (int m = 0; m < 8; ++m)
        af[m] = *(const bf16x8*)&lA[cur][(m * 16 + lr) * BK + swz];
#pragma unroll
      for (int n = 0; n < 4; ++n)
        bfr[n] = *(const bf16x8*)&lB[cur][(w * 64 + n * 16 + lr) * BK + swz];

#pragma unroll
      for (int m = 0; m < 8; ++m)
#pragma unroll
        for (int n = 0; n < 4; ++n)
          acc[m][n] = __builtin_amdgcn_mfma_f32_16x16x32_bf16(af[m], bfr[n], acc[m][n], 0, 0, 0);

      __builtin_amdgcn_sched_barrier(0);
      __builtin_amdgcn_s_barrier();
    }
#undef STAGE_R

    // epilogue: row sums (all), col sums (mirror credit; left half only if strictly upper)
    const int grow0 = rm * 128;
    const int gcolw = cn0 * 128 + w * 64;
    float csum[4] = {0.f, 0.f, 0.f, 0.f};
#pragma unroll
    for (int m = 0; m < 8; ++m) {
#pragma unroll
      for (int j = 0; j < 4; ++j) {
        const int row = m * 16 + lg * 4 + j;
        const int gq = grow0 + row;
        const int prt = gq ^ BS;
        float sse = 0.f;
#pragma unroll
        for (int n = 0; n < 4; ++n) {
          const int gc = gcolw + n * 16 + lr;
          const float v = acc[m][n][j];
          if (gc == prt) { pos[gq] = v; pos[gc] = v; }   // symmetric positive pair
          const float e = (gc != gq) ? __expf(v) : 0.f;  // exclude self-term
          sse += e;
          csum[n] += e;
        }
        sse += __shfl_xor(sse, 1);
        sse += __shfl_xor(sse, 2);
        sse += __shfl_xor(sse, 4);
        sse += __shfl_xor(sse, 8);
        if (lr == 0) psumR[w][row] = sse;
      }
    }
#pragma unroll
    for (int n = 0; n < 4; ++n) {
      csum[n] += __shfl_xor(csum[n], 16);
      csum[n] += __shfl_xor(csum[n], 32);
      if (lg == 0) psumC[w * 64 + n * 16 + lr] = csum[n];
    }
    __syncthreads();
    if (tid < 128)
      atomicAdd(&sumexp[grow0 + tid],
                psumR[0][tid] + psumR[1][tid] + psumR[2][tid] + psumR[3][tid]);
    // col credit: right half (cells cn0+1) always strictly upper; left half only if cn0 != rm
    if (tid >= 128 || cn0 != rm)
      atomicAdd(&sumexp[cn0 * 128 + tid], psumC[tid]);

  } else {
#define STAGE_D(buf)                                                 \
    do {                                                             \
      gload_lds16(gA, &lA[buf][tid * 8]);                            \
      gload_lds16(gA + (size_t)64 * D, &lA[buf][tid * 8 + 64 * BK]); \
      gload_lds16(gB, &lB[buf][tid * 8]);                            \
      gload_lds16(gB + (size_t)64 * D, &lB[buf][tid * 8 + 64 * BK]); \
      gA += BK; gB += BK;                                            \
    } while (0)

    const int wr = w >> 1, wc = w & 1;
    f32x4 acc[4][4] = {};
    STAGE_D(0);
    STAGE_D(1);

    for (int kt = 0; kt < NKT; ++kt) {
      const int cur = kt % 3;
      if (kt < NKT - 2) {
        STAGE_D((kt + 2) % 3);
        asm volatile("s_waitcnt vmcnt(8)");
      } else if (kt == NKT - 2) {
        asm volatile("s_waitcnt vmcnt(4)");
      } else {
        asm volatile("s_waitcnt vmcnt(0)");
      }
      __builtin_amdgcn_s_barrier();
      __builtin_amdgcn_sched_barrier(0);

      bf16x8 af[4], bfr[4];
#pragma unroll
      for (int m = 0; m < 4; ++m)
        af[m] = *(const bf16x8*)&lA[cur][(wr * 64 + m * 16 + lr) * BK + swz];
#pragma unroll
      for (int n = 0; n < 4; ++n)
        bfr[n] = *(const bf16x8*)&lB[cur][(wc * 64 + n * 16 + lr) * BK + swz];

#pragma unroll
      for (int m = 0; m < 4; ++m)
#pragma unroll
        for (int n = 0; n < 4; ++n)
          acc[m][n] = __builtin_amdgcn_mfma_f32_16x16x32_bf16(af[m], bfr[n], acc[m][n], 0, 0, 0);

      __builtin_amdgcn_sched_barrier(0);
      __builtin_amdgcn_s_barrier();
    }
#undef STAGE_D

    // diag epilogue: row sums only (self-exclusion), no pos, no col credit
    const int gr0 = rm * 128 + wr * 64;
    const int gc0 = rm * 128 + wc * 64;
#pragma unroll
    for (int m = 0; m < 4; ++m) {
#pragma unroll
      for (int j = 0; j < 4; ++j) {
        const int gq = gr0 + m * 16 + lg * 4 + j;
        float sse = 0.f;
#pragma unroll
        for (int n = 0; n < 4; ++n) {
          const int gc = gc0 + n * 16 + lr;
          const float v = acc[m][n][j];
          sse += (gc != gq) ? __expf(v) : 0.f;
        }
        sse += __shfl_xor(sse, 1);
        sse += __shfl_xor(sse, 2);
        sse += __shfl_xor(sse, 4);
        sse += __shfl_xor(sse, 8);
        if (lr == 0) psumR[wc][wr * 64 + m * 16 + lg * 4 + j] = sse;
      }
    }
    __syncthreads();
    if (tid < 128)
      atomicAdd(&sumexp[rm * 128 + tid], psumR[0][tid] + psumR[1][tid]);
  }
}

// ---------------- kernel 3: final reduction + KL ----------------
__global__ __launch_bounds__(256) void finalize_kernel(
    const float* __restrict__ sumexp, const float* __restrict__ pos,
    const float* __restrict__ dio, const float* __restrict__ djo,
    float* __restrict__ out) {
  const int tid = threadIdx.x;
  float s1 = 0.f, sa = 0.f, sb = 0.f;
  for (int q = tid; q < M2; q += 256) s1 += __logf(sumexp[q]) - pos[q];
  for (int r = tid; r < BS; r += 256) { sa += __expf(dio[r]); sb += __expf(djo[r]); }

  __shared__ float red[4][3];
  float v3[3] = {s1, sa, sb};
#pragma unroll
  for (int k = 0; k < 3; ++k)
#pragma unroll
    for (int o = 32; o; o >>= 1) v3[k] += __shfl_xor(v3[k], o);
  const int w = tid >> 6, lane = tid & 63;
  if (lane == 0) { red[w][0] = v3[0]; red[w][1] = v3[1]; red[w][2] = v3[2]; }
  __syncthreads();
  const float S1 = red[0][0] + red[1][0] + red[2][0] + red[3][0];
  const float A  = red[0][1] + red[1][1] + red[2][1] + red[3][1];
  const float B  = red[0][2] + red[1][2] + red[2][2] + red[3][2];
  const float logB = __logf(B);
  const float invA = 1.0f / A;

  float kl = 0.f;
  for (int r = tid; r < BS; r += 256) {
    const float lp = djo[r] - logB;            // log_softmax target
    kl += __expf(lp) * (lp - __expf(dio[r]) * invA);
  }
#pragma unroll
  for (int o = 32; o; o >>= 1) kl += __shfl_xor(kl, o);
  __shared__ float red2[4];
  if (lane == 0) red2[w] = kl;
  __syncthreads();
  if (tid == 0) {
    const float KL = red2[0] + red2[1] + red2[2] + red2[3];
    out[0] = S1 / (float)M2 + 0.5f * KL;
  }
}

extern "C" void kernel_launch(void* const* d_in, const int* in_sizes, int n_in,
                              void* d_out, int out_size, void* d_ws, size_t ws_size,
                              hipStream_t stream) {
  const float* zi = (const float*)d_in[0];
  const float* zj = (const float*)d_in[1];
  const float* zo = (const float*)d_in[2];
  char* ws = (char*)d_ws;
  unsigned short* Z = (unsigned short*)(ws + OFF_Z);
  float* sumexp = (float*)(ws + OFF_SUMEXP);
  float* pos    = (float*)(ws + OFF_POS);
  float* dio    = (float*)(ws + OFF_DIO);
  float* djo    = (float*)(ws + OFF_DJO);

  prep_kernel<<<BS, 256, 0, stream>>>(zi, zj, zo, Z, dio, djo, sumexp);
  gemm_lse_kernel<<<NBLK_ALL, 256, 0, stream>>>(Z, sumexp, pos);
  finalize_kernel<<<1, 256, 0, stream>>>(sumexp, pos, dio, djo, (float*)d_out);
}